// Round 7
// baseline (770.314 us; speedup 1.0000x reference)
//
#include <hip/hip_runtime.h>

#define NN 100000
#define EE 1600000
#define EPS 1e-5f
#define NBLK 196  // ceil(NN/512)

__device__ __forceinline__ ushort f2bf(float f) {
    uint u = __float_as_uint(f);
    uint r = (u + 0x7FFF + ((u >> 16) & 1)) >> 16;  // RNE
    return (ushort)r;
}
__device__ __forceinline__ float bf2f(ushort u) {
    return __uint_as_float(((uint)u) << 16);
}

// ---------------- fill zero (float4 grid-stride) ----------------
__global__ void fill0(float4* __restrict__ p, long n4) {
    long i = (long)blockIdx.x * blockDim.x + threadIdx.x;
    long stride = (long)gridDim.x * blockDim.x;
    float4 z = make_float4(0.f, 0.f, 0.f, 0.f);
    for (; i < n4; i += stride) p[i] = z;
}

// ---------------- hist: 4-wide vectorized degree count + CSR pad sentinels ----------------
__global__ __launch_bounds__(256) void hist(const int* __restrict__ ei0, const int* __restrict__ ei1,
                                            int* __restrict__ deg0, int* __restrict__ deg1,
                                            int2* __restrict__ ecsr0, int2* __restrict__ ecsr1) {
    if (blockIdx.x == 0 && threadIdx.x < 32) {
        int i = threadIdx.x;
        if (i < 16) ecsr0[EE + i] = make_int2(0, 0);
        else        ecsr1[EE + i - 16] = make_int2(0, 0);
    }
    long c = (long)blockIdx.x * 256 + threadIdx.x;
    if (c >= EE / 4) return;
    long i = c * 4;
    int4 d0 = *reinterpret_cast<const int4*>(&ei0[EE + i]);
    atomicAdd(&deg0[d0.x], 1);
    atomicAdd(&deg0[d0.y], 1);
    atomicAdd(&deg0[d0.z], 1);
    atomicAdd(&deg0[d0.w], 1);
    int4 d1 = *reinterpret_cast<const int4*>(&ei1[EE + i]);
    atomicAdd(&deg1[d1.x], 1);
    atomicAdd(&deg1[d1.y], 1);
    atomicAdd(&deg1[d1.z], 1);
    atomicAdd(&deg1[d1.w], 1);
}

// ---------------- scanA: per-block (512 deg) sums ----------------
__global__ __launch_bounds__(256) void scanA(const int* __restrict__ deg0,
                                             const int* __restrict__ deg1,
                                             int* __restrict__ bsum) {
    int which = blockIdx.x >= NBLK;
    const int* deg = which ? deg1 : deg0;
    int blk = blockIdx.x - which * NBLK;
    int base = blk * 512 + threadIdx.x * 2;
    int d0 = base < NN ? deg[base] : 0;
    int d1 = base + 1 < NN ? deg[base + 1] : 0;
    int s = d0 + d1;
#pragma unroll
    for (int off = 1; off < 64; off <<= 1) s += __shfl_xor(s, off, 64);
    __shared__ int ws4[4];
    int lane = threadIdx.x & 63, wv = threadIdx.x >> 6;
    if (lane == 0) ws4[wv] = s;
    __syncthreads();
    if (threadIdx.x == 0) bsum[blockIdx.x] = ws4[0] + ws4[1] + ws4[2] + ws4[3];
}

// ---------------- scanB: exclusive scan of block sums (2 segments) ----------------
__global__ __launch_bounds__(256) void scanB(int* __restrict__ bsum) {
    int seg = blockIdx.x;
    int t = threadIdx.x;
    int v = t < NBLK ? bsum[seg * NBLK + t] : 0;
    int x = v;
    int lane = t & 63, wv = t >> 6;
#pragma unroll
    for (int off = 1; off < 64; off <<= 1) {
        int y = __shfl_up(x, off, 64);
        if (lane >= off) x += y;
    }
    __shared__ int wsum[4];
    __shared__ int wpre[4];
    if (lane == 63) wsum[wv] = x;
    __syncthreads();
    if (t == 0) {
        int s = 0;
        for (int i = 0; i < 4; ++i) { wpre[i] = s; s += wsum[i]; }
    }
    __syncthreads();
    if (t < NBLK) bsum[seg * NBLK + t] = wpre[wv] + x - v;  // exclusive
}

// ---------------- scanC: final exclusive scan, write rp + pos ----------------
__global__ __launch_bounds__(256) void scanC(const int* __restrict__ deg0,
                                             const int* __restrict__ deg1,
                                             const int* __restrict__ bsum,
                                             int* __restrict__ rp0, int* __restrict__ pos0,
                                             int* __restrict__ rp1, int* __restrict__ pos1) {
    int which = blockIdx.x >= NBLK;
    const int* deg = which ? deg1 : deg0;
    int* rp  = which ? rp1  : rp0;
    int* pos = which ? pos1 : pos0;
    int blk = blockIdx.x - which * NBLK;
    int base = blk * 512 + threadIdx.x * 2;
    int d0 = base < NN ? deg[base] : 0;
    int d1 = base + 1 < NN ? deg[base + 1] : 0;
    int s = d0 + d1;
    int x = s;
    int lane = threadIdx.x & 63, wv = threadIdx.x >> 6;
#pragma unroll
    for (int off = 1; off < 64; off <<= 1) {
        int y = __shfl_up(x, off, 64);
        if (lane >= off) x += y;
    }
    __shared__ int wsum[4];
    __shared__ int wpre[4];
    if (lane == 63) wsum[wv] = x;
    __syncthreads();
    if (threadIdx.x == 0) {
        int ss = 0;
        for (int i = 0; i < 4; ++i) { wpre[i] = ss; ss += wsum[i]; }
    }
    __syncthreads();
    int excl = bsum[blockIdx.x] + wpre[wv] + x - s;
    if (base < NN)     { rp[base] = excl;           pos[base] = excl; }
    if (base + 1 < NN) { rp[base + 1] = excl + d0;  pos[base + 1] = excl + d0; }
    if (blk == 0 && threadIdx.x == 0) rp[NN] = EE;
}

// ---------------- scat: one 4-edge chunk per thread, 4 atomics in flight ----------------
__global__ __launch_bounds__(256) void scat(const int* __restrict__ ei, const float* __restrict__ ew,
                                            int* __restrict__ pos, int2* __restrict__ ecsr) {
    long c = (long)blockIdx.x * 256 + threadIdx.x;
    if (c >= EE / 4) return;
    long i = c * 4;
    int4 dst4 = *reinterpret_cast<const int4*>(&ei[EE + i]);
    int4 src4 = *reinterpret_cast<const int4*>(&ei[i]);
    float4 w4 = *reinterpret_cast<const float4*>(&ew[i]);
    int k0 = atomicAdd(&pos[dst4.x], 1);
    int k1 = atomicAdd(&pos[dst4.y], 1);
    int k2 = atomicAdd(&pos[dst4.z], 1);
    int k3 = atomicAdd(&pos[dst4.w], 1);
    ecsr[k0] = make_int2(src4.x, __float_as_int(w4.x));
    ecsr[k1] = make_int2(src4.y, __float_as_int(w4.y));
    ecsr[k2] = make_int2(src4.z, __float_as_int(w4.z));
    ecsr[k3] = make_int2(src4.w, __float_as_int(w4.w));
}

// ---------------- prew: WU = W1_2@U2, WV = W1_2@V2 (16x64 each) ----------------
__global__ __launch_bounds__(256) void prew(const float* __restrict__ W1_2,
                                            const float* __restrict__ U2,
                                            const float* __restrict__ V2,
                                            float* __restrict__ WU,
                                            float* __restrict__ WV) {
    int t = threadIdx.x;
    for (int i = t; i < 1024; i += 256) {
        int k = i >> 6, j = i & 63;
        float su = 0.f, sv = 0.f;
        for (int m = 0; m < 64; ++m) {
            float wm = W1_2[k * 64 + m];
            su += wm * U2[m * 64 + j];
            sv += wm * V2[m * 64 + j];
        }
        WU[i] = su;
        WV[i] = sv;
    }
}

// ---------------- k1: x1 = X@W1_1 (wave per node), fp32 + bf16 copies ----------------
__global__ __launch_bounds__(256) void k1(const float* __restrict__ X,
                                          const float* __restrict__ W1,
                                          float* __restrict__ x1,
                                          ushort* __restrict__ x1g) {
    __shared__ float Ws[128 * 16];
    __shared__ float Xs[4][4][132];  // wave, b, c (+4 pad)
    int t = threadIdx.x;
    for (int i = t; i < 2048; i += 256) Ws[i] = W1[i];
    int w = t >> 6, lane = t & 63;
    int n = blockIdx.x * 4 + w;
    for (int bb = 0; bb < 2; ++bb) {
        int b = bb * 2 + (lane >> 5);
        int c4 = (lane & 31) * 4;
        float4 v = *reinterpret_cast<const float4*>(&X[((long)b * NN + n) * 128 + c4]);
        *reinterpret_cast<float4*>(&Xs[w][b][c4]) = v;
    }
    __syncthreads();
    int b = lane >> 4, h = lane & 15;
    float acc = 0.f;
#pragma unroll 8
    for (int c = 0; c < 128; ++c) acc += Xs[w][b][c] * Ws[c * 16 + h];
    x1[(long)n * 64 + lane] = acc;
    x1g[(long)n * 64 + lane] = f2bf(acc);
}

// ---------------- k3: layer1 gather+epilogue -> h1 fp32 + h1g bf16 ----------------
__global__ __launch_bounds__(256) void k3(const float* __restrict__ x1,
                                          const ushort* __restrict__ x1g,
                                          const int2* __restrict__ ecsr0,
                                          const int* __restrict__ rp0,
                                          const float* __restrict__ W2_1,
                                          const float* __restrict__ U1,
                                          const float* __restrict__ V1,
                                          float* __restrict__ h1out,
                                          ushort* __restrict__ h1g) {
    __shared__ float U1s[256];
    __shared__ float V1s[256];
    __shared__ float W21s[16];
    __shared__ float x1s[4][64];
    __shared__ float aggs[4][64];
    int t = threadIdx.x;
    U1s[t] = U1[t];
    V1s[t] = V1[t];
    if (t < 16) W21s[t] = W2_1[t];
    int w = t >> 6, lane = t & 63;
    int n = blockIdx.x * 4 + w;
    __syncthreads();
    float xr = x1[(long)n * 64 + lane];
    int start = rp0[n], end = rp0[n + 1];
    float acc = 0.f;
    for (int e = start; e < end; e += 16) {
        int2 r[16];
#pragma unroll
        for (int i = 0; i < 16; ++i) r[i] = ecsr0[e + i];  // memory-safe (global pad)
        float v[16];
#pragma unroll
        for (int i = 0; i < 16; ++i) v[i] = bf2f(x1g[(long)r[i].x * 64 + lane]);
#pragma unroll
        for (int i = 0; i < 16; ++i) {
            float wm = (e + i < end) ? __int_as_float(r[i].y) : 0.f;  // mask tail
            acc += wm * v[i];
        }
    }
    x1s[w][lane] = xr;
    aggs[w][lane] = acc;
    int b = lane >> 4, h = lane & 15;
    float av = 0.f, xu = 0.f;
#pragma unroll
    for (int k = 0; k < 16; ++k) {
        av += aggs[w][b * 16 + k] * V1s[k * 16 + h];
        xu += x1s[w][b * 16 + k] * U1s[k * 16 + h];
    }
    float c = fmaxf((float)(end - start), 1.f);
    float a = xu + W21s[h] * av / c;
    float s = a, s2 = a * a;
#pragma unroll
    for (int off = 32; off >= 1; off >>= 1) {
        s += __shfl_xor(s, off, 64);
        s2 += __shfl_xor(s2, off, 64);
    }
    float mean = s * (1.f / 64.f);
    float var = s2 * (1.f / 64.f) - mean * mean;
    float norm = (a - mean) * rsqrtf(var + EPS);
    float hv = xr + fmaxf(norm, 0.f);
    h1out[(long)n * 64 + lane] = hv;
    h1g[(long)n * 64 + lane] = f2bf(hv);
}

// ---------------- k5: layer2 gather(h1g)+epilogue -> out ----------------
__global__ __launch_bounds__(256) void k5(const float* __restrict__ h1,
                                          const ushort* __restrict__ h1g,
                                          const int2* __restrict__ ecsr1,
                                          const int* __restrict__ rp1,
                                          const float* __restrict__ W2_2,
                                          const float* __restrict__ W1_2,
                                          const float* __restrict__ WU,
                                          const float* __restrict__ WV,
                                          float* __restrict__ out) {
    __shared__ float W12s[1024];
    __shared__ float WUs[1024];
    __shared__ float WVs[1024];
    __shared__ float W22s[64];
    __shared__ float h1s[4][64];
    __shared__ float aggs[4][64];
    int t = threadIdx.x;
    for (int i = t; i < 1024; i += 256) {
        W12s[i] = W1_2[i];
        WUs[i] = WU[i];
        WVs[i] = WV[i];
    }
    if (t < 64) W22s[t] = W2_2[t];
    int w = t >> 6, lane = t & 63;
    int n = blockIdx.x * 4 + w;
    __syncthreads();
    float hv = h1[(long)n * 64 + lane];
    int start = rp1[n], end = rp1[n + 1];
    float acc = 0.f;
    for (int e = start; e < end; e += 16) {
        int2 r[16];
#pragma unroll
        for (int i = 0; i < 16; ++i) r[i] = ecsr1[e + i];  // memory-safe (global pad)
        float v[16];
#pragma unroll
        for (int i = 0; i < 16; ++i) v[i] = bf2f(h1g[(long)r[i].x * 64 + lane]);
#pragma unroll
        for (int i = 0; i < 16; ++i) {
            float wm = (e + i < end) ? __int_as_float(r[i].y) : 0.f;  // mask tail
            acc += wm * v[i];
        }
    }
    h1s[w][lane] = hv;
    aggs[w][lane] = acc;
    float c = fmaxf((float)(end - start), 1.f);
    float x2b[4], ab[4];
    float s = 0.f, s2 = 0.f;
#pragma unroll
    for (int b = 0; b < 4; ++b) {
        float x2 = 0.f, xu = 0.f, av = 0.f;
#pragma unroll
        for (int k = 0; k < 16; ++k) {
            float hk = h1s[w][b * 16 + k];
            float gk = aggs[w][b * 16 + k];
            x2 += hk * W12s[k * 64 + lane];
            xu += hk * WUs[k * 64 + lane];
            av += gk * WVs[k * 64 + lane];
        }
        float a = xu + W22s[lane] * av / c;
        x2b[b] = x2;
        ab[b] = a;
        s += a;
        s2 += a * a;
    }
#pragma unroll
    for (int off = 32; off >= 1; off >>= 1) {
        s += __shfl_xor(s, off, 64);
        s2 += __shfl_xor(s2, off, 64);
    }
    float mean = s * (1.f / 256.f);
    float var = s2 * (1.f / 256.f) - mean * mean;
    float rs = rsqrtf(var + EPS);
#pragma unroll
    for (int b = 0; b < 4; ++b) {
        float norm = (ab[b] - mean) * rs;
        out[((long)b * NN + n) * 64 + lane] = x2b[b] + fmaxf(norm, 0.f);
    }
}

extern "C" void kernel_launch(void* const* d_in, const int* in_sizes, int n_in,
                              void* d_out, int out_size, void* d_ws, size_t ws_size,
                              hipStream_t stream) {
    const float* X    = (const float*)d_in[0];
    const int*   ei0  = (const int*)d_in[1];
    const float* ew0  = (const float*)d_in[2];
    const int*   ei1  = (const int*)d_in[3];
    const float* ew1  = (const float*)d_in[4];
    const float* W1_1 = (const float*)d_in[8];
    const float* W2_1 = (const float*)d_in[9];
    const float* U1   = (const float*)d_in[10];
    const float* V1   = (const float*)d_in[11];
    const float* W1_2 = (const float*)d_in[12];
    const float* W2_2 = (const float*)d_in[13];
    const float* U2   = (const float*)d_in[14];
    const float* V2   = (const float*)d_in[15];
    float* out = (float*)d_out;
    char* ws = (char*)d_ws;

    const long MB = 1000000L;
    float*  x1   = (float*)(ws + 0L);             // 25.6 MB
    float*  h1   = (float*)(ws + 26 * MB);        // 25.6 MB
    int*    deg0 = (int*)(ws + 52 * MB);          // 400 KB
    int*    deg1 = (int*)(ws + 52 * MB + 400000L);
    int*    bsum = (int*)(ws + 52 * MB + 800000L); // 392 ints
    int*    rp0  = (int*)(ws + 53 * MB);
    int*    pos0 = (int*)(ws + 54 * MB);
    int*    rp1  = (int*)(ws + 55 * MB);
    int*    pos1 = (int*)(ws + 56 * MB);
    int2*   ecsr0 = (int2*)(ws + 57 * MB);        // 12.8 MB + 128 B pad
    int2*   ecsr1 = (int2*)(ws + 70 * MB);        // 12.8 MB + 128 B pad
    float*  WU   = (float*)(ws + 83 * MB);        // 4 KB
    float*  WV   = (float*)(ws + 83 * MB + 4096);
    ushort* x1g  = (ushort*)(ws + 84 * MB);       // 12.8 MB
    ushort* h1g  = (ushort*)(ws + 97 * MB);       // 12.8 MB (ends 109.8 MB)

    fill0<<<196, 256, 0, stream>>>((float4*)deg0, 800000L / 16);
    hist<<<1563, 256, 0, stream>>>(ei0, ei1, deg0, deg1, ecsr0, ecsr1);
    scanA<<<2 * NBLK, 256, 0, stream>>>(deg0, deg1, bsum);
    scanB<<<2, 256, 0, stream>>>(bsum);
    scanC<<<2 * NBLK, 256, 0, stream>>>(deg0, deg1, bsum, rp0, pos0, rp1, pos1);
    scat<<<1563, 256, 0, stream>>>(ei0, ew0, pos0, ecsr0);
    scat<<<1563, 256, 0, stream>>>(ei1, ew1, pos1, ecsr1);
    prew<<<1, 256, 0, stream>>>(W1_2, U2, V2, WU, WV);
    k1<<<25000, 256, 0, stream>>>(X, W1_1, x1, x1g);
    k3<<<25000, 256, 0, stream>>>(x1, x1g, ecsr0, rp0, W2_1, U1, V1, h1, h1g);
    k5<<<25000, 256, 0, stream>>>(h1, h1g, ecsr1, rp1, W2_2, W1_2, WU, WV, out);
}

// Round 8
// 514.127 us; speedup vs baseline: 1.4983x; 1.4983x over previous
//
#include <hip/hip_runtime.h>

#define NN 100000
#define EE 1600000
#define EPS 1e-5f
#define NBLK 196   // ceil(NN/512)
#define HBLK 1563  // ceil(EE/4/256)

__device__ __forceinline__ ushort f2bf(float f) {
    uint u = __float_as_uint(f);
    uint r = (u + 0x7FFF + ((u >> 16) & 1)) >> 16;  // RNE
    return (ushort)r;
}
__device__ __forceinline__ float bf2f(ushort u) {
    return __uint_as_float(((uint)u) << 16);
}

// ---------------- fill zero (float4 grid-stride) ----------------
__global__ void fill0(float4* __restrict__ p, long n4) {
    long i = (long)blockIdx.x * blockDim.x + threadIdx.x;
    long stride = (long)gridDim.x * blockDim.x;
    float4 z = make_float4(0.f, 0.f, 0.f, 0.f);
    for (; i < n4; i += stride) p[i] = z;
}

// ---------------- k1h: x1g = bf16(X@W1_1), fused hist(+rank) for both lists ----------------
__global__ __launch_bounds__(256) void k1h(const float* __restrict__ X,
                                           const float* __restrict__ W1,
                                           ushort* __restrict__ x1g,
                                           const int* __restrict__ ei0, const int* __restrict__ ei1,
                                           int* __restrict__ deg0, int* __restrict__ deg1,
                                           int* __restrict__ rank0, int* __restrict__ rank1) {
    // hist part: first HBLK blocks each cover 4 edges/thread of both lists.
    // atomic returns feed only stores -> no wave stall.
    long c = (long)blockIdx.x * 256 + threadIdx.x;
    if (blockIdx.x < HBLK && c < EE / 4) {
        long i = c * 4;
        int4 d0 = *reinterpret_cast<const int4*>(&ei0[EE + i]);
        int4 rk;
        rk.x = atomicAdd(&deg0[d0.x], 1);
        rk.y = atomicAdd(&deg0[d0.y], 1);
        rk.z = atomicAdd(&deg0[d0.z], 1);
        rk.w = atomicAdd(&deg0[d0.w], 1);
        *reinterpret_cast<int4*>(&rank0[i]) = rk;
        int4 d1 = *reinterpret_cast<const int4*>(&ei1[EE + i]);
        int4 rk1;
        rk1.x = atomicAdd(&deg1[d1.x], 1);
        rk1.y = atomicAdd(&deg1[d1.y], 1);
        rk1.z = atomicAdd(&deg1[d1.z], 1);
        rk1.w = atomicAdd(&deg1[d1.w], 1);
        *reinterpret_cast<int4*>(&rank1[i]) = rk1;
    }
    // GEMM part: wave per node
    __shared__ float Ws[128 * 16];
    __shared__ float Xs[4][4][132];  // wave, b, c (+4 pad)
    int t = threadIdx.x;
    for (int i = t; i < 2048; i += 256) Ws[i] = W1[i];
    int w = t >> 6, lane = t & 63;
    int n = blockIdx.x * 4 + w;
    for (int bb = 0; bb < 2; ++bb) {
        int b = bb * 2 + (lane >> 5);
        int c4 = (lane & 31) * 4;
        float4 v = *reinterpret_cast<const float4*>(&X[((long)b * NN + n) * 128 + c4]);
        *reinterpret_cast<float4*>(&Xs[w][b][c4]) = v;
    }
    __syncthreads();
    int b = lane >> 4, h = lane & 15;
    float acc = 0.f;
#pragma unroll 8
    for (int cc = 0; cc < 128; ++cc) acc += Xs[w][b][cc] * Ws[cc * 16 + h];
    x1g[(long)n * 64 + lane] = f2bf(acc);
}

// ---------------- scanA: per-block (512 deg) sums ----------------
__global__ __launch_bounds__(256) void scanA(const int* __restrict__ deg0,
                                             const int* __restrict__ deg1,
                                             int* __restrict__ bsum) {
    int which = blockIdx.x >= NBLK;
    const int* deg = which ? deg1 : deg0;
    int blk = blockIdx.x - which * NBLK;
    int base = blk * 512 + threadIdx.x * 2;
    int d0 = base < NN ? deg[base] : 0;
    int d1 = base + 1 < NN ? deg[base + 1] : 0;
    int s = d0 + d1;
#pragma unroll
    for (int off = 1; off < 64; off <<= 1) s += __shfl_xor(s, off, 64);
    __shared__ int ws4[4];
    int lane = threadIdx.x & 63, wv = threadIdx.x >> 6;
    if (lane == 0) ws4[wv] = s;
    __syncthreads();
    if (threadIdx.x == 0) bsum[blockIdx.x] = ws4[0] + ws4[1] + ws4[2] + ws4[3];
}

// ---------------- scanBp: exclusive scan of block sums (blocks 0,1) + prew (block 2) ----------------
__global__ __launch_bounds__(256) void scanBp(int* __restrict__ bsum,
                                              const float* __restrict__ W1_2,
                                              const float* __restrict__ U2,
                                              const float* __restrict__ V2,
                                              float* __restrict__ WU,
                                              float* __restrict__ WV) {
    int t = threadIdx.x;
    if (blockIdx.x == 2) {  // prew: WU = W1_2@U2, WV = W1_2@V2
        for (int i = t; i < 1024; i += 256) {
            int k = i >> 6, j = i & 63;
            float su = 0.f, sv = 0.f;
            for (int m = 0; m < 64; ++m) {
                float wm = W1_2[k * 64 + m];
                su += wm * U2[m * 64 + j];
                sv += wm * V2[m * 64 + j];
            }
            WU[i] = su;
            WV[i] = sv;
        }
        return;
    }
    int seg = blockIdx.x;
    int v = t < NBLK ? bsum[seg * NBLK + t] : 0;
    int x = v;
    int lane = t & 63, wv = t >> 6;
#pragma unroll
    for (int off = 1; off < 64; off <<= 1) {
        int y = __shfl_up(x, off, 64);
        if (lane >= off) x += y;
    }
    __shared__ int wsum[4];
    __shared__ int wpre[4];
    if (lane == 63) wsum[wv] = x;
    __syncthreads();
    if (t == 0) {
        int s = 0;
        for (int i = 0; i < 4; ++i) { wpre[i] = s; s += wsum[i]; }
    }
    __syncthreads();
    if (t < NBLK) bsum[seg * NBLK + t] = wpre[wv] + x - v;  // exclusive
}

// ---------------- scanC: final exclusive scan, write rp ----------------
__global__ __launch_bounds__(256) void scanC(const int* __restrict__ deg0,
                                             const int* __restrict__ deg1,
                                             const int* __restrict__ bsum,
                                             int* __restrict__ rp0, int* __restrict__ rp1) {
    int which = blockIdx.x >= NBLK;
    const int* deg = which ? deg1 : deg0;
    int* rp = which ? rp1 : rp0;
    int blk = blockIdx.x - which * NBLK;
    int base = blk * 512 + threadIdx.x * 2;
    int d0 = base < NN ? deg[base] : 0;
    int d1 = base + 1 < NN ? deg[base + 1] : 0;
    int s = d0 + d1;
    int x = s;
    int lane = threadIdx.x & 63, wv = threadIdx.x >> 6;
#pragma unroll
    for (int off = 1; off < 64; off <<= 1) {
        int y = __shfl_up(x, off, 64);
        if (lane >= off) x += y;
    }
    __shared__ int wsum[4];
    __shared__ int wpre[4];
    if (lane == 63) wsum[wv] = x;
    __syncthreads();
    if (threadIdx.x == 0) {
        int ss = 0;
        for (int i = 0; i < 4; ++i) { wpre[i] = ss; ss += wsum[i]; }
    }
    __syncthreads();
    int excl = bsum[blockIdx.x] + wpre[wv] + x - s;
    if (base < NN)     rp[base] = excl;
    if (base + 1 < NN) rp[base + 1] = excl + d0;
    if (blk == 0 && threadIdx.x == 0) rp[NN] = EE;
}

// ---------------- scat2: atomic-free scatter (slot = rp[dst]+rank[e]), both lists ----------------
__global__ __launch_bounds__(256) void scat2(const int* __restrict__ ei0, const float* __restrict__ ew0,
                                             const int* __restrict__ rank0, const int* __restrict__ rp0,
                                             int2* __restrict__ ecsr0,
                                             const int* __restrict__ ei1, const float* __restrict__ ew1,
                                             const int* __restrict__ rank1, const int* __restrict__ rp1,
                                             int2* __restrict__ ecsr1) {
    if (blockIdx.x == 0 && threadIdx.x < 32) {
        int i = threadIdx.x;
        if (i < 16) ecsr0[EE + i] = make_int2(0, 0);
        else        ecsr1[EE + i - 16] = make_int2(0, 0);
    }
    int which = blockIdx.x >= HBLK;
    const int* ei = which ? ei1 : ei0;
    const float* ew = which ? ew1 : ew0;
    const int* rank = which ? rank1 : rank0;
    const int* rp = which ? rp1 : rp0;
    int2* ecsr = which ? ecsr1 : ecsr0;
    long c = (long)(blockIdx.x - which * HBLK) * 256 + threadIdx.x;
    if (c >= EE / 4) return;
    long i = c * 4;
    int4 dst4 = *reinterpret_cast<const int4*>(&ei[EE + i]);
    int4 src4 = *reinterpret_cast<const int4*>(&ei[i]);
    int4 rk4  = *reinterpret_cast<const int4*>(&rank[i]);
    float4 w4 = *reinterpret_cast<const float4*>(&ew[i]);
    int s0 = rp[dst4.x] + rk4.x;
    int s1 = rp[dst4.y] + rk4.y;
    int s2 = rp[dst4.z] + rk4.z;
    int s3 = rp[dst4.w] + rk4.w;
    // store pre-scaled byte offsets (src*128) for the gather kernels
    ecsr[s0] = make_int2(src4.x << 7, __float_as_int(w4.x));
    ecsr[s1] = make_int2(src4.y << 7, __float_as_int(w4.y));
    ecsr[s2] = make_int2(src4.z << 7, __float_as_int(w4.z));
    ecsr[s3] = make_int2(src4.w << 7, __float_as_int(w4.w));
}

// ---------------- k3: layer1 gather+epilogue -> h1g bf16 (wave per node) ----------------
__global__ __launch_bounds__(256) void k3(const ushort* __restrict__ x1g,
                                          const int2* __restrict__ ecsr0,
                                          const int* __restrict__ rp0,
                                          const float* __restrict__ W2_1,
                                          const float* __restrict__ U1,
                                          const float* __restrict__ V1,
                                          ushort* __restrict__ h1g) {
    __shared__ float U1s[256];
    __shared__ float V1s[256];
    __shared__ float W21s[16];
    __shared__ float x1s[4][64];
    __shared__ float aggs[4][64];
    int t = threadIdx.x;
    U1s[t] = U1[t];
    V1s[t] = V1[t];
    if (t < 16) W21s[t] = W2_1[t];
    int w = t >> 6, lane = t & 63;
    int n = blockIdx.x * 4 + w;
    __syncthreads();
    const char* xb = (const char*)x1g;
    int lb = lane << 1;
    float xr = bf2f(x1g[(long)n * 64 + lane]);
    int start = rp0[n], end = rp0[n + 1];
    float acc = 0.f;
    int e = start;
    int efull = start + ((end - start) & ~15);
    for (; e < efull; e += 16) {  // full chunks: no mask
        int2 r[16];
#pragma unroll
        for (int i = 0; i < 16; ++i) r[i] = ecsr0[e + i];
        float v[16];
#pragma unroll
        for (int i = 0; i < 16; ++i)
            v[i] = bf2f(*(const ushort*)(xb + (uint)r[i].x + lb));
#pragma unroll
        for (int i = 0; i < 16; ++i) acc += __int_as_float(r[i].y) * v[i];
    }
    if (e < end) {  // masked tail (memory-safe via global pad)
        int2 r[16];
#pragma unroll
        for (int i = 0; i < 16; ++i) r[i] = ecsr0[e + i];
        float v[16];
#pragma unroll
        for (int i = 0; i < 16; ++i)
            v[i] = bf2f(*(const ushort*)(xb + (uint)r[i].x + lb));
#pragma unroll
        for (int i = 0; i < 16; ++i) {
            float wm = (e + i < end) ? __int_as_float(r[i].y) : 0.f;
            acc += wm * v[i];
        }
    }
    x1s[w][lane] = xr;
    aggs[w][lane] = acc;
    int b = lane >> 4, h = lane & 15;
    float av = 0.f, xu = 0.f;
#pragma unroll
    for (int k = 0; k < 16; ++k) {
        av += aggs[w][b * 16 + k] * V1s[k * 16 + h];
        xu += x1s[w][b * 16 + k] * U1s[k * 16 + h];
    }
    float c = fmaxf((float)(end - start), 1.f);
    float a = xu + W21s[h] * av / c;
    float s = a, s2 = a * a;
#pragma unroll
    for (int off = 32; off >= 1; off >>= 1) {
        s += __shfl_xor(s, off, 64);
        s2 += __shfl_xor(s2, off, 64);
    }
    float mean = s * (1.f / 64.f);
    float var = s2 * (1.f / 64.f) - mean * mean;
    float norm = (a - mean) * rsqrtf(var + EPS);
    float hv = xr + fmaxf(norm, 0.f);
    h1g[(long)n * 64 + lane] = f2bf(hv);
}

// ---------------- k5: layer2 gather(h1g)+epilogue -> out (wave per node) ----------------
__global__ __launch_bounds__(256) void k5(const ushort* __restrict__ h1g,
                                          const int2* __restrict__ ecsr1,
                                          const int* __restrict__ rp1,
                                          const float* __restrict__ W2_2,
                                          const float* __restrict__ W1_2,
                                          const float* __restrict__ WU,
                                          const float* __restrict__ WV,
                                          float* __restrict__ out) {
    __shared__ float W12s[1024];
    __shared__ float WUs[1024];
    __shared__ float WVs[1024];
    __shared__ float W22s[64];
    __shared__ float h1s[4][64];
    __shared__ float aggs[4][64];
    int t = threadIdx.x;
    for (int i = t; i < 1024; i += 256) {
        W12s[i] = W1_2[i];
        WUs[i] = WU[i];
        WVs[i] = WV[i];
    }
    if (t < 64) W22s[t] = W2_2[t];
    int w = t >> 6, lane = t & 63;
    int n = blockIdx.x * 4 + w;
    __syncthreads();
    const char* hb = (const char*)h1g;
    int lb = lane << 1;
    float hv = bf2f(h1g[(long)n * 64 + lane]);
    int start = rp1[n], end = rp1[n + 1];
    float acc = 0.f;
    int e = start;
    int efull = start + ((end - start) & ~15);
    for (; e < efull; e += 16) {  // full chunks: no mask
        int2 r[16];
#pragma unroll
        for (int i = 0; i < 16; ++i) r[i] = ecsr1[e + i];
        float v[16];
#pragma unroll
        for (int i = 0; i < 16; ++i)
            v[i] = bf2f(*(const ushort*)(hb + (uint)r[i].x + lb));
#pragma unroll
        for (int i = 0; i < 16; ++i) acc += __int_as_float(r[i].y) * v[i];
    }
    if (e < end) {  // masked tail
        int2 r[16];
#pragma unroll
        for (int i = 0; i < 16; ++i) r[i] = ecsr1[e + i];
        float v[16];
#pragma unroll
        for (int i = 0; i < 16; ++i)
            v[i] = bf2f(*(const ushort*)(hb + (uint)r[i].x + lb));
#pragma unroll
        for (int i = 0; i < 16; ++i) {
            float wm = (e + i < end) ? __int_as_float(r[i].y) : 0.f;
            acc += wm * v[i];
        }
    }
    h1s[w][lane] = hv;
    aggs[w][lane] = acc;
    float c = fmaxf((float)(end - start), 1.f);
    float x2b[4], ab[4];
    float s = 0.f, s2 = 0.f;
#pragma unroll
    for (int b = 0; b < 4; ++b) {
        float x2 = 0.f, xu = 0.f, av = 0.f;
#pragma unroll
        for (int k = 0; k < 16; ++k) {
            float hk = h1s[w][b * 16 + k];
            float gk = aggs[w][b * 16 + k];
            x2 += hk * W12s[k * 64 + lane];
            xu += hk * WUs[k * 64 + lane];
            av += gk * WVs[k * 64 + lane];
        }
        float a = xu + W22s[lane] * av / c;
        x2b[b] = x2;
        ab[b] = a;
        s += a;
        s2 += a * a;
    }
#pragma unroll
    for (int off = 32; off >= 1; off >>= 1) {
        s += __shfl_xor(s, off, 64);
        s2 += __shfl_xor(s2, off, 64);
    }
    float mean = s * (1.f / 256.f);
    float var = s2 * (1.f / 256.f) - mean * mean;
    float rs = rsqrtf(var + EPS);
#pragma unroll
    for (int b = 0; b < 4; ++b) {
        float norm = (ab[b] - mean) * rs;
        out[((long)b * NN + n) * 64 + lane] = x2b[b] + fmaxf(norm, 0.f);
    }
}

extern "C" void kernel_launch(void* const* d_in, const int* in_sizes, int n_in,
                              void* d_out, int out_size, void* d_ws, size_t ws_size,
                              hipStream_t stream) {
    const float* X    = (const float*)d_in[0];
    const int*   ei0  = (const int*)d_in[1];
    const float* ew0  = (const float*)d_in[2];
    const int*   ei1  = (const int*)d_in[3];
    const float* ew1  = (const float*)d_in[4];
    const float* W1_1 = (const float*)d_in[8];
    const float* W2_1 = (const float*)d_in[9];
    const float* U1   = (const float*)d_in[10];
    const float* V1   = (const float*)d_in[11];
    const float* W1_2 = (const float*)d_in[12];
    const float* W2_2 = (const float*)d_in[13];
    const float* U2   = (const float*)d_in[14];
    const float* V2   = (const float*)d_in[15];
    float* out = (float*)d_out;
    char* ws = (char*)d_ws;

    const long MB = 1000000L;
    ushort* x1g  = (ushort*)(ws + 0L);            // 12.8 MB
    ushort* h1g  = (ushort*)(ws + 13 * MB);       // 12.8 MB
    int*    deg0 = (int*)(ws + 26 * MB);          // 400 KB
    int*    deg1 = (int*)(ws + 26 * MB + 400000L);// 400 KB
    int*    bsum = (int*)(ws + 26 * MB + 800000L);// 1.6 KB
    int*    rp0  = (int*)(ws + 27 * MB);          // 400 KB + 4
    int*    rp1  = (int*)(ws + 28 * MB);
    int*    rank0 = (int*)(ws + 29 * MB);         // 6.4 MB
    int*    rank1 = (int*)(ws + 36 * MB);         // 6.4 MB
    int2*   ecsr0 = (int2*)(ws + 43 * MB);        // 12.8 MB + 128 B pad
    int2*   ecsr1 = (int2*)(ws + 56 * MB);        // 12.8 MB + 128 B pad
    float*  WU   = (float*)(ws + 69 * MB);        // 4 KB
    float*  WV   = (float*)(ws + 69 * MB + 4096);

    fill0<<<196, 256, 0, stream>>>((float4*)deg0, 800000L / 16);
    k1h<<<25000, 256, 0, stream>>>(X, W1_1, x1g, ei0, ei1, deg0, deg1, rank0, rank1);
    scanA<<<2 * NBLK, 256, 0, stream>>>(deg0, deg1, bsum);
    scanBp<<<3, 256, 0, stream>>>(bsum, W1_2, U2, V2, WU, WV);
    scanC<<<2 * NBLK, 256, 0, stream>>>(deg0, deg1, bsum, rp0, rp1);
    scat2<<<2 * HBLK, 256, 0, stream>>>(ei0, ew0, rank0, rp0, ecsr0, ei1, ew1, rank1, rp1, ecsr1);
    k3<<<25000, 256, 0, stream>>>(x1g, ecsr0, rp0, W2_1, U1, V1, h1g);
    k5<<<25000, 256, 0, stream>>>(h1g, ecsr1, rp1, W2_2, W1_2, WU, WV, out);
}

// Round 9
// 500.305 us; speedup vs baseline: 1.5397x; 1.0276x over previous
//
#include <hip/hip_runtime.h>

#define NN 100000
#define EE 1600000
#define EPS 1e-5f
#define NBLK 196   // ceil(NN/512)
#define HBLK 1563  // ceil(EE/4/256)

__device__ __forceinline__ ushort f2bf(float f) {
    uint u = __float_as_uint(f);
    uint r = (u + 0x7FFF + ((u >> 16) & 1)) >> 16;  // RNE
    return (ushort)r;
}
__device__ __forceinline__ float bf2f(ushort u) {
    return __uint_as_float(((uint)u) << 16);
}

// ---------------- fill zero (float4 grid-stride) ----------------
__global__ void fill0(float4* __restrict__ p, long n4) {
    long i = (long)blockIdx.x * blockDim.x + threadIdx.x;
    long stride = (long)gridDim.x * blockDim.x;
    float4 z = make_float4(0.f, 0.f, 0.f, 0.f);
    for (; i < n4; i += stride) p[i] = z;
}

// ---------------- k1h: x1g = bf16(X@W1_1) (16 nodes/block) + fused hist/rank ----------------
__global__ __launch_bounds__(256) void k1h(const float* __restrict__ X,
                                           const float* __restrict__ W1,
                                           ushort* __restrict__ x1g,
                                           const int* __restrict__ ei0, const int* __restrict__ ei1,
                                           int* __restrict__ deg0, int* __restrict__ deg1,
                                           int* __restrict__ rank0, int* __restrict__ rank1) {
    // hist part: first HBLK blocks, 4 edges/thread/list; atomic returns feed only stores.
    long ce = (long)blockIdx.x * 256 + threadIdx.x;
    if (blockIdx.x < HBLK && ce < EE / 4) {
        long i = ce * 4;
        int4 d0 = *reinterpret_cast<const int4*>(&ei0[EE + i]);
        int4 rk;
        rk.x = atomicAdd(&deg0[d0.x], 1);
        rk.y = atomicAdd(&deg0[d0.y], 1);
        rk.z = atomicAdd(&deg0[d0.z], 1);
        rk.w = atomicAdd(&deg0[d0.w], 1);
        *reinterpret_cast<int4*>(&rank0[i]) = rk;
        int4 d1 = *reinterpret_cast<const int4*>(&ei1[EE + i]);
        int4 rk1;
        rk1.x = atomicAdd(&deg1[d1.x], 1);
        rk1.y = atomicAdd(&deg1[d1.y], 1);
        rk1.z = atomicAdd(&deg1[d1.z], 1);
        rk1.w = atomicAdd(&deg1[d1.w], 1);
        *reinterpret_cast<int4*>(&rank1[i]) = rk1;
    }
    // GEMM: block = 16 nodes, wave = 4 nodes
    __shared__ __align__(16) float Xs[64][132];  // [n_loc*4+b][c], 528B row (16B-aligned, conflict-free)
    int t = threadIdx.x;
    int w = t >> 6, lane = t & 63;
    int nb = blockIdx.x * 16;
#pragma unroll
    for (int i = 0; i < 8; ++i) {
        int flat = i * 256 + t;            // (n_loc:4b, b:2b, c4:5b) = 16*4*32
        int n_loc = flat >> 7;
        int b = (flat >> 5) & 3;
        int c4 = (flat & 31) << 2;
        float4 v = *reinterpret_cast<const float4*>(&X[((long)b * NN + (nb + n_loc)) * 128 + c4]);
        *reinterpret_cast<float4*>(&Xs[n_loc * 4 + b][c4]) = v;
    }
    __syncthreads();
    int b = lane >> 4, h = lane & 15;
    float acc[4] = {0.f, 0.f, 0.f, 0.f};
    for (int c0 = 0; c0 < 128; c0 += 32) {
        float wreg[32];
#pragma unroll
        for (int j = 0; j < 32; ++j) wreg[j] = W1[(c0 + j) * 16 + h];
#pragma unroll
        for (int ni = 0; ni < 4; ++ni) {
            int row = (w * 4 + ni) * 4 + b;
            float a = 0.f;
#pragma unroll
            for (int j8 = 0; j8 < 8; ++j8) {
                float4 xv = *reinterpret_cast<const float4*>(&Xs[row][c0 + j8 * 4]);
                a += xv.x * wreg[j8 * 4] + xv.y * wreg[j8 * 4 + 1]
                   + xv.z * wreg[j8 * 4 + 2] + xv.w * wreg[j8 * 4 + 3];
            }
            acc[ni] += a;
        }
    }
#pragma unroll
    for (int ni = 0; ni < 4; ++ni)
        x1g[(long)(nb + w * 4 + ni) * 64 + lane] = f2bf(acc[ni]);
}

// ---------------- scanA: per-block (512 deg) sums ----------------
__global__ __launch_bounds__(256) void scanA(const int* __restrict__ deg0,
                                             const int* __restrict__ deg1,
                                             int* __restrict__ bsum) {
    int which = blockIdx.x >= NBLK;
    const int* deg = which ? deg1 : deg0;
    int blk = blockIdx.x - which * NBLK;
    int base = blk * 512 + threadIdx.x * 2;
    int d0 = base < NN ? deg[base] : 0;
    int d1 = base + 1 < NN ? deg[base + 1] : 0;
    int s = d0 + d1;
#pragma unroll
    for (int off = 1; off < 64; off <<= 1) s += __shfl_xor(s, off, 64);
    __shared__ int ws4[4];
    int lane = threadIdx.x & 63, wv = threadIdx.x >> 6;
    if (lane == 0) ws4[wv] = s;
    __syncthreads();
    if (threadIdx.x == 0) bsum[blockIdx.x] = ws4[0] + ws4[1] + ws4[2] + ws4[3];
}

// ---------------- scanBp: exclusive scan of block sums (blocks 0,1) + prew (block 2) ----------------
__global__ __launch_bounds__(256) void scanBp(int* __restrict__ bsum,
                                              const float* __restrict__ W1_2,
                                              const float* __restrict__ U2,
                                              const float* __restrict__ V2,
                                              float* __restrict__ WU,
                                              float* __restrict__ WV) {
    int t = threadIdx.x;
    if (blockIdx.x == 2) {  // prew: WU = W1_2@U2, WV = W1_2@V2
        for (int i = t; i < 1024; i += 256) {
            int k = i >> 6, j = i & 63;
            float su = 0.f, sv = 0.f;
            for (int m = 0; m < 64; ++m) {
                float wm = W1_2[k * 64 + m];
                su += wm * U2[m * 64 + j];
                sv += wm * V2[m * 64 + j];
            }
            WU[i] = su;
            WV[i] = sv;
        }
        return;
    }
    int seg = blockIdx.x;
    int v = t < NBLK ? bsum[seg * NBLK + t] : 0;
    int x = v;
    int lane = t & 63, wv = t >> 6;
#pragma unroll
    for (int off = 1; off < 64; off <<= 1) {
        int y = __shfl_up(x, off, 64);
        if (lane >= off) x += y;
    }
    __shared__ int wsum[4];
    __shared__ int wpre[4];
    if (lane == 63) wsum[wv] = x;
    __syncthreads();
    if (t == 0) {
        int s = 0;
        for (int i = 0; i < 4; ++i) { wpre[i] = s; s += wsum[i]; }
    }
    __syncthreads();
    if (t < NBLK) bsum[seg * NBLK + t] = wpre[wv] + x - v;  // exclusive
}

// ---------------- scanC: final exclusive scan, write rp ----------------
__global__ __launch_bounds__(256) void scanC(const int* __restrict__ deg0,
                                             const int* __restrict__ deg1,
                                             const int* __restrict__ bsum,
                                             int* __restrict__ rp0, int* __restrict__ rp1) {
    int which = blockIdx.x >= NBLK;
    const int* deg = which ? deg1 : deg0;
    int* rp = which ? rp1 : rp0;
    int blk = blockIdx.x - which * NBLK;
    int base = blk * 512 + threadIdx.x * 2;
    int d0 = base < NN ? deg[base] : 0;
    int d1 = base + 1 < NN ? deg[base + 1] : 0;
    int s = d0 + d1;
    int x = s;
    int lane = threadIdx.x & 63, wv = threadIdx.x >> 6;
#pragma unroll
    for (int off = 1; off < 64; off <<= 1) {
        int y = __shfl_up(x, off, 64);
        if (lane >= off) x += y;
    }
    __shared__ int wsum[4];
    __shared__ int wpre[4];
    if (lane == 63) wsum[wv] = x;
    __syncthreads();
    if (threadIdx.x == 0) {
        int ss = 0;
        for (int i = 0; i < 4; ++i) { wpre[i] = ss; ss += wsum[i]; }
    }
    __syncthreads();
    int excl = bsum[blockIdx.x] + wpre[wv] + x - s;
    if (base < NN)     rp[base] = excl;
    if (base + 1 < NN) rp[base + 1] = excl + d0;
    if (blk == 0 && threadIdx.x == 0) rp[NN] = EE;
}

// ---------------- scat2: atomic-free scatter (slot = rp[dst]+rank[e]), both lists ----------------
__global__ __launch_bounds__(256) void scat2(const int* __restrict__ ei0, const float* __restrict__ ew0,
                                             const int* __restrict__ rank0, const int* __restrict__ rp0,
                                             int2* __restrict__ ecsr0,
                                             const int* __restrict__ ei1, const float* __restrict__ ew1,
                                             const int* __restrict__ rank1, const int* __restrict__ rp1,
                                             int2* __restrict__ ecsr1) {
    if (blockIdx.x == 0 && threadIdx.x < 32) {
        int i = threadIdx.x;
        if (i < 16) ecsr0[EE + i] = make_int2(0, 0);
        else        ecsr1[EE + i - 16] = make_int2(0, 0);
    }
    int which = blockIdx.x >= HBLK;
    const int* ei = which ? ei1 : ei0;
    const float* ew = which ? ew1 : ew0;
    const int* rank = which ? rank1 : rank0;
    const int* rp = which ? rp1 : rp0;
    int2* ecsr = which ? ecsr1 : ecsr0;
    long c = (long)(blockIdx.x - which * HBLK) * 256 + threadIdx.x;
    if (c >= EE / 4) return;
    long i = c * 4;
    int4 dst4 = *reinterpret_cast<const int4*>(&ei[EE + i]);
    int4 src4 = *reinterpret_cast<const int4*>(&ei[i]);
    int4 rk4  = *reinterpret_cast<const int4*>(&rank[i]);
    float4 w4 = *reinterpret_cast<const float4*>(&ew[i]);
    int s0 = rp[dst4.x] + rk4.x;
    int s1 = rp[dst4.y] + rk4.y;
    int s2 = rp[dst4.z] + rk4.z;
    int s3 = rp[dst4.w] + rk4.w;
    // store pre-scaled byte offsets (src*128) for the gather kernels
    ecsr[s0] = make_int2(src4.x << 7, __float_as_int(w4.x));
    ecsr[s1] = make_int2(src4.y << 7, __float_as_int(w4.y));
    ecsr[s2] = make_int2(src4.z << 7, __float_as_int(w4.z));
    ecsr[s3] = make_int2(src4.w << 7, __float_as_int(w4.w));
}

// ---------------- k3: layer1 gather+epilogue -> h1g bf16 (wave per node) ----------------
__global__ __launch_bounds__(256) void k3(const ushort* __restrict__ x1g,
                                          const int2* __restrict__ ecsr0,
                                          const int* __restrict__ rp0,
                                          const float* __restrict__ W2_1,
                                          const float* __restrict__ U1,
                                          const float* __restrict__ V1,
                                          ushort* __restrict__ h1g) {
    __shared__ float x1s[4][64];
    __shared__ float aggs[4][64];
    int t = threadIdx.x;
    int w = t >> 6, lane = t & 63;
    int b = lane >> 4, h = lane & 15;
    // register-hoisted weight columns (L1-resident, coalesced)
    float ureg[16], vreg[16];
#pragma unroll
    for (int k = 0; k < 16; ++k) { ureg[k] = U1[k * 16 + h]; vreg[k] = V1[k * 16 + h]; }
    float w21 = W2_1[h];
    int n = blockIdx.x * 4 + w;
    const char* xb = (const char*)x1g;
    int lb = lane << 1;
    float xr = bf2f(x1g[(long)n * 64 + lane]);
    int start = rp0[n], end = rp0[n + 1];
    float acc = 0.f;
    int e = start;
    int efull = start + ((end - start) & ~15);
    for (; e < efull; e += 16) {  // full chunks: no mask
        int2 r[16];
#pragma unroll
        for (int i = 0; i < 16; ++i) r[i] = ecsr0[e + i];
        float v[16];
#pragma unroll
        for (int i = 0; i < 16; ++i)
            v[i] = bf2f(*(const ushort*)(xb + (uint)r[i].x + lb));
#pragma unroll
        for (int i = 0; i < 16; ++i) acc += __int_as_float(r[i].y) * v[i];
    }
    if (e < end) {  // masked tail (memory-safe via global pad)
        int2 r[16];
#pragma unroll
        for (int i = 0; i < 16; ++i) r[i] = ecsr0[e + i];
        float v[16];
#pragma unroll
        for (int i = 0; i < 16; ++i)
            v[i] = bf2f(*(const ushort*)(xb + (uint)r[i].x + lb));
#pragma unroll
        for (int i = 0; i < 16; ++i) {
            float wm = (e + i < end) ? __int_as_float(r[i].y) : 0.f;
            acc += wm * v[i];
        }
    }
    x1s[w][lane] = xr;
    aggs[w][lane] = acc;
    float av = 0.f, xu = 0.f;
#pragma unroll
    for (int k = 0; k < 16; ++k) {
        av += aggs[w][b * 16 + k] * vreg[k];
        xu += x1s[w][b * 16 + k] * ureg[k];
    }
    float c = fmaxf((float)(end - start), 1.f);
    float a = xu + w21 * av / c;
    float s = a, s2 = a * a;
#pragma unroll
    for (int off = 32; off >= 1; off >>= 1) {
        s += __shfl_xor(s, off, 64);
        s2 += __shfl_xor(s2, off, 64);
    }
    float mean = s * (1.f / 64.f);
    float var = s2 * (1.f / 64.f) - mean * mean;
    float norm = (a - mean) * rsqrtf(var + EPS);
    float hv = xr + fmaxf(norm, 0.f);
    h1g[(long)n * 64 + lane] = f2bf(hv);
}

// ---------------- k5: layer2 gather(h1g)+epilogue -> out (wave per node) ----------------
__global__ __launch_bounds__(256) void k5(const ushort* __restrict__ h1g,
                                          const int2* __restrict__ ecsr1,
                                          const int* __restrict__ rp1,
                                          const float* __restrict__ W2_2,
                                          const float* __restrict__ W1_2,
                                          const float* __restrict__ WU,
                                          const float* __restrict__ WV,
                                          float* __restrict__ out) {
    __shared__ float h1s[4][64];
    __shared__ float aggs[4][64];
    int t = threadIdx.x;
    int w = t >> 6, lane = t & 63;
    // register-hoisted weight columns (L1-resident, coalesced)
    float w12r[16], wur[16], wvr[16];
#pragma unroll
    for (int k = 0; k < 16; ++k) {
        w12r[k] = W1_2[k * 64 + lane];
        wur[k]  = WU[k * 64 + lane];
        wvr[k]  = WV[k * 64 + lane];
    }
    float w22 = W2_2[lane];
    int n = blockIdx.x * 4 + w;
    const char* hb = (const char*)h1g;
    int lb = lane << 1;
    float hv = bf2f(h1g[(long)n * 64 + lane]);
    int start = rp1[n], end = rp1[n + 1];
    float acc = 0.f;
    int e = start;
    int efull = start + ((end - start) & ~15);
    for (; e < efull; e += 16) {  // full chunks: no mask
        int2 r[16];
#pragma unroll
        for (int i = 0; i < 16; ++i) r[i] = ecsr1[e + i];
        float v[16];
#pragma unroll
        for (int i = 0; i < 16; ++i)
            v[i] = bf2f(*(const ushort*)(hb + (uint)r[i].x + lb));
#pragma unroll
        for (int i = 0; i < 16; ++i) acc += __int_as_float(r[i].y) * v[i];
    }
    if (e < end) {  // masked tail
        int2 r[16];
#pragma unroll
        for (int i = 0; i < 16; ++i) r[i] = ecsr1[e + i];
        float v[16];
#pragma unroll
        for (int i = 0; i < 16; ++i)
            v[i] = bf2f(*(const ushort*)(hb + (uint)r[i].x + lb));
#pragma unroll
        for (int i = 0; i < 16; ++i) {
            float wm = (e + i < end) ? __int_as_float(r[i].y) : 0.f;
            acc += wm * v[i];
        }
    }
    h1s[w][lane] = hv;
    aggs[w][lane] = acc;
    float c = fmaxf((float)(end - start), 1.f);
    float x2b[4], ab[4];
    float s = 0.f, s2 = 0.f;
#pragma unroll
    for (int b = 0; b < 4; ++b) {
        float x2 = 0.f, xu = 0.f, av = 0.f;
#pragma unroll
        for (int k = 0; k < 16; ++k) {
            float hk = h1s[w][b * 16 + k];
            float gk = aggs[w][b * 16 + k];
            x2 += hk * w12r[k];
            xu += hk * wur[k];
            av += gk * wvr[k];
        }
        float a = xu + w22 * av / c;
        x2b[b] = x2;
        ab[b] = a;
        s += a;
        s2 += a * a;
    }
#pragma unroll
    for (int off = 32; off >= 1; off >>= 1) {
        s += __shfl_xor(s, off, 64);
        s2 += __shfl_xor(s2, off, 64);
    }
    float mean = s * (1.f / 256.f);
    float var = s2 * (1.f / 256.f) - mean * mean;
    float rs = rsqrtf(var + EPS);
#pragma unroll
    for (int b = 0; b < 4; ++b) {
        float norm = (ab[b] - mean) * rs;
        out[((long)b * NN + n) * 64 + lane] = x2b[b] + fmaxf(norm, 0.f);
    }
}

extern "C" void kernel_launch(void* const* d_in, const int* in_sizes, int n_in,
                              void* d_out, int out_size, void* d_ws, size_t ws_size,
                              hipStream_t stream) {
    const float* X    = (const float*)d_in[0];
    const int*   ei0  = (const int*)d_in[1];
    const float* ew0  = (const float*)d_in[2];
    const int*   ei1  = (const int*)d_in[3];
    const float* ew1  = (const float*)d_in[4];
    const float* W1_1 = (const float*)d_in[8];
    const float* W2_1 = (const float*)d_in[9];
    const float* U1   = (const float*)d_in[10];
    const float* V1   = (const float*)d_in[11];
    const float* W1_2 = (const float*)d_in[12];
    const float* W2_2 = (const float*)d_in[13];
    const float* U2   = (const float*)d_in[14];
    const float* V2   = (const float*)d_in[15];
    float* out = (float*)d_out;
    char* ws = (char*)d_ws;

    const long MB = 1000000L;
    ushort* x1g  = (ushort*)(ws + 0L);            // 12.8 MB
    ushort* h1g  = (ushort*)(ws + 13 * MB);       // 12.8 MB
    int*    deg0 = (int*)(ws + 26 * MB);          // 400 KB
    int*    deg1 = (int*)(ws + 26 * MB + 400000L);// 400 KB
    int*    bsum = (int*)(ws + 26 * MB + 800000L);// 1.6 KB
    int*    rp0  = (int*)(ws + 27 * MB);          // 400 KB + 4
    int*    rp1  = (int*)(ws + 28 * MB);
    int*    rank0 = (int*)(ws + 29 * MB);         // 6.4 MB
    int*    rank1 = (int*)(ws + 36 * MB);         // 6.4 MB
    int2*   ecsr0 = (int2*)(ws + 43 * MB);        // 12.8 MB + 128 B pad
    int2*   ecsr1 = (int2*)(ws + 56 * MB);        // 12.8 MB + 128 B pad
    float*  WU   = (float*)(ws + 69 * MB);        // 4 KB
    float*  WV   = (float*)(ws + 69 * MB + 4096);

    fill0<<<196, 256, 0, stream>>>((float4*)deg0, 800000L / 16);
    k1h<<<6250, 256, 0, stream>>>(X, W1_1, x1g, ei0, ei1, deg0, deg1, rank0, rank1);
    scanA<<<2 * NBLK, 256, 0, stream>>>(deg0, deg1, bsum);
    scanBp<<<3, 256, 0, stream>>>(bsum, W1_2, U2, V2, WU, WV);
    scanC<<<2 * NBLK, 256, 0, stream>>>(deg0, deg1, bsum, rp0, rp1);
    scat2<<<2 * HBLK, 256, 0, stream>>>(ei0, ew0, rank0, rp0, ecsr0, ei1, ew1, rank1, rp1, ecsr1);
    k3<<<25000, 256, 0, stream>>>(x1g, ecsr0, rp0, W2_1, U1, V1, h1g);
    k5<<<25000, 256, 0, stream>>>(h1g, ecsr1, rp1, W2_2, W1_2, WU, WV, out);
}